// Round 1
// baseline (10760.735 us; speedup 1.0000x reference)
//
#include <hip/hip_runtime.h>

// KEPCE_GAT: 2-layer GATv2 + fused affine edge-MLP on MI355X.
// Structure: degree pass -> per-layer {node-pre, edge-A (alpha/amax),
// node-mid (self-loop init), edge-B (atomic accumulate num/den), node-out}
// -> node-final (fc + folded edge-MLP node terms) -> edge-final.

__device__ __forceinline__ float lrelu(float v){ return v > 0.f ? v : 0.2f*v; }

// float atomic max via int punning (finite values only).
__device__ __forceinline__ void atomicMaxF(float* addr, float v){
  if (v >= 0.f) atomicMax((int*)addr, __float_as_int(v));
  else          atomicMin((unsigned int*)addr, __float_as_uint(v));
}

// Fold edge MLP: Wc[66,2] = w_e1[66,32] @ w_e2[32,2]; bc[2] = b_e1@w_e2 + b_e2.
__global__ void k_wcomb(const float* __restrict__ we1, const float* __restrict__ be1,
                        const float* __restrict__ we2, const float* __restrict__ be2,
                        float* __restrict__ wc, float* __restrict__ bc){
  int t = threadIdx.x;
  if (t < 132){
    int i = t >> 1, k = t & 1;
    float acc = 0.f;
    for (int j = 0; j < 32; ++j) acc += we1[i*32+j]*we2[j*2+k];
    wc[t] = acc;
  } else if (t < 134){
    int k = t - 132;
    float acc = be2[k];
    for (int j = 0; j < 32; ++j) acc += be1[j]*we2[j*2+k];
    bc[k] = acc;
  }
}

// h0 = relu(x @ w_init + b_init), x:[n,5] -> h0:[n,8]
__global__ void k_node_init(const float* __restrict__ x, const float* __restrict__ w,
                            const float* __restrict__ b, float* __restrict__ h0, int n){
  int i = blockIdx.x*blockDim.x + threadIdx.x;
  if (i >= n) return;
  float xi[5];
  #pragma unroll
  for (int j = 0; j < 5; ++j) xi[j] = x[i*5+j];
  #pragma unroll
  for (int o = 0; o < 8; ++o){
    float acc = b[o];
    #pragma unroll
    for (int j = 0; j < 5; ++j) acc += xi[j]*w[j*8+o];
    h0[i*8+o] = fmaxf(acc, 0.f);
  }
}

// Incoming-degree count + edge-attr sum per dst (for self-loop 'mean' fill).
__global__ void k_edge_deg(const int* __restrict__ ei, const float* __restrict__ ew,
                           const float* __restrict__ ce, float* __restrict__ cnt,
                           float* __restrict__ sattr, int E){
  int e = blockIdx.x*blockDim.x + threadIdx.x;
  if (e >= E) return;
  int d = ei[E+e];
  atomicAdd(&cnt[d], 1.f);
  atomicAdd(&sattr[2*d],   ew[e]);
  atomicAdd(&sattr[2*d+1], ce[e]);
}

// Per-node: xl = hin@Wl+bl, xr = hin@Wr+br; self-loop alpha; amax init = alpha_self.
template<int IN, int C>
__global__ void k_node_pre(const float* __restrict__ hin,
                           const float* __restrict__ wl, const float* __restrict__ bl,
                           const float* __restrict__ wr, const float* __restrict__ br,
                           const float* __restrict__ we, const float* __restrict__ att,
                           const float* __restrict__ cnt, const float* __restrict__ sattr,
                           float* __restrict__ xl, float* __restrict__ xr,
                           float* __restrict__ aself, float* __restrict__ amax, int n){
  constexpr int HC = 4*C;
  int i = blockIdx.x*blockDim.x + threadIdx.x;
  if (i >= n) return;
  float h[IN];
  #pragma unroll
  for (int j = 0; j < IN; ++j) h[j] = hin[i*IN+j];
  float inv = 1.f / fmaxf(cnt[i], 1.f);
  float l0 = sattr[2*i]*inv, l1 = sattr[2*i+1]*inv;
  float XL[HC], XR[HC];
  #pragma unroll
  for (int o = 0; o < HC; ++o){
    float a = bl[o], r = br[o];
    #pragma unroll
    for (int j = 0; j < IN; ++j){ a += h[j]*wl[j*HC+o]; r += h[j]*wr[j*HC+o]; }
    XL[o] = a; XR[o] = r;
    xl[i*HC+o] = a; xr[i*HC+o] = r;
  }
  #pragma unroll
  for (int hh = 0; hh < 4; ++hh){
    float acc = 0.f;
    #pragma unroll
    for (int c = 0; c < C; ++c){
      int o = hh*C + c;
      float m = XL[o] + XR[o] + l0*we[o] + l1*we[HC+o];
      acc += att[o]*lrelu(m);
    }
    aself[i*4+hh] = acc;
    amax[i*4+hh]  = acc;
  }
}

// Self-loop contribution: den = exp(aself-amax); num = den * xl.
template<int C>
__global__ void k_node_mid(const float* __restrict__ xl, const float* __restrict__ aself,
                           const float* __restrict__ amax, float* __restrict__ den,
                           float* __restrict__ num, int n){
  constexpr int HC = 4*C;
  int i = blockIdx.x*blockDim.x + threadIdx.x;
  if (i >= n) return;
  #pragma unroll
  for (int hh = 0; hh < 4; ++hh){
    float ex = __expf(aself[i*4+hh] - amax[i*4+hh]);
    den[i*4+hh] = ex;
    #pragma unroll
    for (int c = 0; c < C; ++c)
      num[i*HC + hh*C + c] = ex * xl[i*HC + hh*C + c];
  }
}

// Edge pass A: alpha per (edge, head) -> atomicMax into amax[dst].
template<int C>
__global__ void k_edge_A(const int* __restrict__ ei, const float* __restrict__ ew,
                         const float* __restrict__ ce, const float* __restrict__ xl,
                         const float* __restrict__ xr, const float* __restrict__ we,
                         const float* __restrict__ att, float* __restrict__ amax, int E){
  constexpr int HC = 4*C;
  int e = blockIdx.x*blockDim.x + threadIdx.x;
  if (e >= E) return;
  int s = ei[e], d = ei[E+e];
  float f0 = ew[e], f1 = ce[e];
  float XL[HC], XR[HC];
  const float4* ps = (const float4*)(xl + (size_t)s*HC);
  const float4* pd = (const float4*)(xr + (size_t)d*HC);
  #pragma unroll
  for (int k = 0; k < HC/4; ++k){
    float4 a = ps[k]; float4 b = pd[k];
    XL[4*k]=a.x; XL[4*k+1]=a.y; XL[4*k+2]=a.z; XL[4*k+3]=a.w;
    XR[4*k]=b.x; XR[4*k+1]=b.y; XR[4*k+2]=b.z; XR[4*k+3]=b.w;
  }
  #pragma unroll
  for (int hh = 0; hh < 4; ++hh){
    float acc = 0.f;
    #pragma unroll
    for (int c = 0; c < C; ++c){
      int o = hh*C + c;
      float m = XL[o] + XR[o] + f0*we[o] + f1*we[HC+o];
      acc += att[o]*lrelu(m);
    }
    atomicMaxF(&amax[d*4+hh], acc);
  }
}

// Edge pass B: recompute alpha, ex = exp(alpha - amax[dst]);
// den[dst] += ex; num[dst] += ex * xl[src].
template<int C>
__global__ void k_edge_B(const int* __restrict__ ei, const float* __restrict__ ew,
                         const float* __restrict__ ce, const float* __restrict__ xl,
                         const float* __restrict__ xr, const float* __restrict__ we,
                         const float* __restrict__ att, const float* __restrict__ amax,
                         float* __restrict__ den, float* __restrict__ num, int E){
  constexpr int HC = 4*C;
  int e = blockIdx.x*blockDim.x + threadIdx.x;
  if (e >= E) return;
  int s = ei[e], d = ei[E+e];
  float f0 = ew[e], f1 = ce[e];
  float XL[HC], XR[HC];
  const float4* ps = (const float4*)(xl + (size_t)s*HC);
  const float4* pd = (const float4*)(xr + (size_t)d*HC);
  #pragma unroll
  for (int k = 0; k < HC/4; ++k){
    float4 a = ps[k]; float4 b = pd[k];
    XL[4*k]=a.x; XL[4*k+1]=a.y; XL[4*k+2]=a.z; XL[4*k+3]=a.w;
    XR[4*k]=b.x; XR[4*k+1]=b.y; XR[4*k+2]=b.z; XR[4*k+3]=b.w;
  }
  #pragma unroll
  for (int hh = 0; hh < 4; ++hh){
    float acc = 0.f;
    #pragma unroll
    for (int c = 0; c < C; ++c){
      int o = hh*C + c;
      float m = XL[o] + XR[o] + f0*we[o] + f1*we[HC+o];
      acc += att[o]*lrelu(m);
    }
    float ex = __expf(acc - amax[d*4+hh]);
    atomicAdd(&den[d*4+hh], ex);
    #pragma unroll
    for (int c = 0; c < C; ++c)
      atomicAdd(&num[(size_t)d*HC + hh*C + c], ex * XL[hh*C + c]);
  }
}

// hout = relu(num/den + bias)
template<int C>
__global__ void k_node_out(const float* __restrict__ num, const float* __restrict__ den,
                           const float* __restrict__ bias, float* __restrict__ hout, int n){
  constexpr int HC = 4*C;
  int i = blockIdx.x*blockDim.x + threadIdx.x;
  if (i >= n) return;
  #pragma unroll
  for (int o = 0; o < HC; ++o){
    int hh = o / C;
    hout[i*HC+o] = fmaxf(num[i*HC+o]/den[i*4+hh] + bias[o], 0.f);
  }
}

// h2 = relu(num/den + bias2); hfc = relu(h2@w_fc+b_fc);
// asrc = hfc @ Wc[2:34], bdst = hfc @ Wc[34:66]  (folded edge-MLP node terms).
__global__ void k_node_final(const float* __restrict__ num, const float* __restrict__ den,
                             const float* __restrict__ bias2, const float* __restrict__ wfc,
                             const float* __restrict__ bfc, const float* __restrict__ wc,
                             float* __restrict__ asrc, float* __restrict__ bdst, int n){
  int i = blockIdx.x*blockDim.x + threadIdx.x;
  if (i >= n) return;
  float h2[32];
  #pragma unroll
  for (int o = 0; o < 32; ++o){
    int hh = o >> 3;
    h2[o] = fmaxf(num[(size_t)i*32+o]/den[i*4+hh] + bias2[o], 0.f);
  }
  float a0=0.f, a1=0.f, b0=0.f, b1=0.f;
  for (int o = 0; o < 32; ++o){
    float acc = bfc[o];
    #pragma unroll
    for (int j = 0; j < 32; ++j) acc += h2[j]*wfc[j*32+o];
    float f = fmaxf(acc, 0.f);
    a0 += f*wc[(2+o)*2];   a1 += f*wc[(2+o)*2+1];
    b0 += f*wc[(34+o)*2];  b1 += f*wc[(34+o)*2+1];
  }
  asrc[2*i]=a0; asrc[2*i+1]=a1; bdst[2*i]=b0; bdst[2*i+1]=b1;
}

// out[e] = ef[e]@Wc[0:2] + asrc[src] + bdst[dst] + bc
__global__ void k_edge_final(const int* __restrict__ ei, const float* __restrict__ ew,
                             const float* __restrict__ ce, const float* __restrict__ asrc,
                             const float* __restrict__ bdst, const float* __restrict__ wc,
                             const float* __restrict__ bc, float* __restrict__ out, int E){
  int e = blockIdx.x*blockDim.x + threadIdx.x;
  if (e >= E) return;
  int s = ei[e], d = ei[E+e];
  float f0 = ew[e], f1 = ce[e];
  out[2*e]   = f0*wc[0] + f1*wc[2] + asrc[2*s]   + bdst[2*d]   + bc[0];
  out[2*e+1] = f0*wc[1] + f1*wc[3] + asrc[2*s+1] + bdst[2*d+1] + bc[1];
}

extern "C" void kernel_launch(void* const* d_in, const int* in_sizes, int n_in,
                              void* d_out, int out_size, void* d_ws, size_t ws_size,
                              hipStream_t stream){
  const float* x     = (const float*)d_in[0];
  const int*   ei    = (const int*)  d_in[1];
  const float* ew    = (const float*)d_in[2];
  const float* ce    = (const float*)d_in[3];
  const float* w_init= (const float*)d_in[4];
  const float* b_init= (const float*)d_in[5];
  const float* w1l   = (const float*)d_in[6];
  const float* b1l   = (const float*)d_in[7];
  const float* w1r   = (const float*)d_in[8];
  const float* b1r   = (const float*)d_in[9];
  const float* w1e   = (const float*)d_in[10];
  const float* att1  = (const float*)d_in[11];
  const float* bias1 = (const float*)d_in[12];
  const float* w2l   = (const float*)d_in[13];
  const float* b2l   = (const float*)d_in[14];
  const float* w2r   = (const float*)d_in[15];
  const float* b2r   = (const float*)d_in[16];
  const float* w2e   = (const float*)d_in[17];
  const float* att2  = (const float*)d_in[18];
  const float* bias2 = (const float*)d_in[19];
  const float* w_fc  = (const float*)d_in[20];
  const float* b_fc  = (const float*)d_in[21];
  const float* w_e1  = (const float*)d_in[22];
  const float* b_e1  = (const float*)d_in[23];
  const float* w_e2  = (const float*)d_in[24];
  const float* b_e2  = (const float*)d_in[25];
  float* out = (float*)d_out;

  const int n = in_sizes[0]/5;     // 100000
  const int E = in_sizes[2];       // 3200000

  // Workspace layout (floats). Persistent: cnt(1), sattr(2), h1(16),
  // asrc(2), bdst(2), wc/bc(256). Scratch region S reused by layer2.
  float* W     = (float*)d_ws;
  float* cnt   = W;
  float* sattr = W + (size_t)n;
  float* h1    = W + (size_t)3*n;
  float* asrc  = W + (size_t)19*n;
  float* bdst  = W + (size_t)21*n;
  float* wc    = W + (size_t)23*n;
  float* bc    = wc + 132;
  float* S     = W + (size_t)23*n + 256;
  // layer1 scratch (68n)
  float* h0    = S;
  float* xl1   = S + (size_t)8*n;
  float* xr1   = S + (size_t)24*n;
  float* as1   = S + (size_t)40*n;
  float* am1   = S + (size_t)44*n;
  float* den1  = S + (size_t)48*n;
  float* num1  = S + (size_t)52*n;
  // layer2 scratch (108n), reuses S — layer1 scratch dead by then
  float* xl2   = S;
  float* xr2   = S + (size_t)32*n;
  float* as2   = S + (size_t)64*n;
  float* am2   = S + (size_t)68*n;
  float* den2  = S + (size_t)72*n;
  float* num2  = S + (size_t)76*n;

  dim3 blk(256);
  dim3 ge((E + 255)/256), gn((n + 255)/256);

  hipMemsetAsync(d_ws, 0, (size_t)3*n*sizeof(float), stream);  // cnt + sattr
  k_wcomb<<<1,192,0,stream>>>(w_e1,b_e1,w_e2,b_e2,wc,bc);
  k_node_init<<<gn,blk,0,stream>>>(x,w_init,b_init,h0,n);
  k_edge_deg<<<ge,blk,0,stream>>>(ei,ew,ce,cnt,sattr,E);

  // ---- GATv2 layer 1 (in 8, C=4, HC=16) ----
  k_node_pre<8,4><<<gn,blk,0,stream>>>(h0,w1l,b1l,w1r,b1r,w1e,att1,cnt,sattr,xl1,xr1,as1,am1,n);
  k_edge_A<4><<<ge,blk,0,stream>>>(ei,ew,ce,xl1,xr1,w1e,att1,am1,E);
  k_node_mid<4><<<gn,blk,0,stream>>>(xl1,as1,am1,den1,num1,n);
  k_edge_B<4><<<ge,blk,0,stream>>>(ei,ew,ce,xl1,xr1,w1e,att1,am1,den1,num1,E);
  k_node_out<4><<<gn,blk,0,stream>>>(num1,den1,bias1,h1,n);

  // ---- GATv2 layer 2 (in 16, C=8, HC=32) ----
  k_node_pre<16,8><<<gn,blk,0,stream>>>(h1,w2l,b2l,w2r,b2r,w2e,att2,cnt,sattr,xl2,xr2,as2,am2,n);
  k_edge_A<8><<<ge,blk,0,stream>>>(ei,ew,ce,xl2,xr2,w2e,att2,am2,E);
  k_node_mid<8><<<gn,blk,0,stream>>>(xl2,as2,am2,den2,num2,n);
  k_edge_B<8><<<ge,blk,0,stream>>>(ei,ew,ce,xl2,xr2,w2e,att2,am2,den2,num2,E);

  // ---- fc + folded edge MLP ----
  k_node_final<<<gn,blk,0,stream>>>(num2,den2,bias2,w_fc,b_fc,wc,asrc,bdst,n);
  k_edge_final<<<ge,blk,0,stream>>>(ei,ew,ce,asrc,bdst,wc,bc,out,E);
}

// Round 2
// 1293.264 us; speedup vs baseline: 8.3206x; 8.3206x over previous
//
#include <hip/hip_runtime.h>

// KEPCE_GAT r2: CSR-based dst-owned aggregation, zero fp atomics.
// Pipeline: hist -> scan -> scatter(CSR) -> loop_attr
//   -> per layer: node_pre (xl,xr GEMM) -> node_agg (fused online-softmax,
//      self-loop, num/den, relu+bias -> hout; all in registers)
//   -> node_final (fc + folded affine edge-MLP) -> edge_final.

__device__ __forceinline__ float lrelu(float v){ return v > 0.f ? v : 0.2f*v; }

// Fold edge MLP: Wc[66,2] = w_e1[66,32] @ w_e2[32,2]; bc[2] = b_e1@w_e2 + b_e2.
__global__ void k_wcomb(const float* __restrict__ we1, const float* __restrict__ be1,
                        const float* __restrict__ we2, const float* __restrict__ be2,
                        float* __restrict__ wc, float* __restrict__ bc){
  int t = threadIdx.x;
  if (t < 132){
    int i = t >> 1, k = t & 1;
    float acc = 0.f;
    for (int j = 0; j < 32; ++j) acc += we1[i*32+j]*we2[j*2+k];
    wc[t] = acc;
  } else if (t < 134){
    int k = t - 132;
    float acc = be2[k];
    for (int j = 0; j < 32; ++j) acc += be1[j]*we2[j*2+k];
    bc[k] = acc;
  }
}

// h0 = relu(x @ w_init + b_init), x:[n,5] -> h0:[n,8]
__global__ void k_node_init(const float* __restrict__ x, const float* __restrict__ w,
                            const float* __restrict__ b, float* __restrict__ h0, int n){
  int i = blockIdx.x*blockDim.x + threadIdx.x;
  if (i >= n) return;
  float xi[5];
  #pragma unroll
  for (int j = 0; j < 5; ++j) xi[j] = x[i*5+j];
  #pragma unroll
  for (int o = 0; o < 8; ++o){
    float acc = b[o];
    #pragma unroll
    for (int j = 0; j < 5; ++j) acc += xi[j]*w[j*8+o];
    h0[i*8+o] = fmaxf(acc, 0.f);
  }
}

// In-degree histogram.
__global__ void k_hist(const int* __restrict__ ei, int* __restrict__ deg, int E){
  int e = blockIdx.x*blockDim.x + threadIdx.x;
  if (e >= E) return;
  atomicAdd(&deg[ei[E+e]], 1);
}

// Exclusive scan over deg[n] -> rowstart[n+1]; wptr = copy. One block, 1024 thr.
__global__ void k_scan(const int* __restrict__ deg, int* __restrict__ rowstart,
                       int* __restrict__ wptr, int n){
  __shared__ int lds[1024];
  int t = threadIdx.x;
  int chunk = (n + 1023) >> 10;
  int lo = t*chunk, hi = min(n, lo+chunk);
  int s = 0;
  for (int k = lo; k < hi; ++k) s += deg[k];
  lds[t] = s;
  __syncthreads();
  for (int off = 1; off < 1024; off <<= 1){
    int v = (t >= off) ? lds[t-off] : 0;
    __syncthreads();
    lds[t] += v;
    __syncthreads();
  }
  int run = (t == 0) ? 0 : lds[t-1];
  for (int k = lo; k < hi; ++k){
    rowstart[k] = run; wptr[k] = run; run += deg[k];
  }
  if (t == 1023) rowstart[n] = lds[1023];
}

// Scatter edges into CSR order (grouped by dst), permuting src + edge attrs.
__global__ void k_scatter(const int* __restrict__ ei, const float* __restrict__ ew,
                          const float* __restrict__ ce, int* __restrict__ wptr,
                          int* __restrict__ csr_src, float* __restrict__ csr_w,
                          float* __restrict__ csr_c, int E){
  int e = blockIdx.x*blockDim.x + threadIdx.x;
  if (e >= E) return;
  int s = ei[e], d = ei[E+e];
  int pos = atomicAdd(&wptr[d], 1);
  csr_src[pos] = s;
  csr_w[pos]   = ew[e];
  csr_c[pos]   = ce[e];
}

// Per-node mean of incoming edge attrs (self-loop fill_value='mean').
__global__ void k_loopattr(const int* __restrict__ rowstart, const float* __restrict__ csr_w,
                           const float* __restrict__ csr_c, float* __restrict__ la, int n){
  int i = blockIdx.x*blockDim.x + threadIdx.x;
  if (i >= n) return;
  int rs = rowstart[i], re = rowstart[i+1];
  float sw = 0.f, sc = 0.f;
  for (int j = rs; j < re; ++j){ sw += csr_w[j]; sc += csr_c[j]; }
  float inv = 1.f / fmaxf((float)(re - rs), 1.f);
  la[2*i]   = sw*inv;
  la[2*i+1] = sc*inv;
}

// xl = hin@Wl+bl, xr = hin@Wr+br.
template<int IN, int C>
__global__ void k_node_pre(const float* __restrict__ hin,
                           const float* __restrict__ wl, const float* __restrict__ bl,
                           const float* __restrict__ wr, const float* __restrict__ br,
                           float* __restrict__ xl, float* __restrict__ xr, int n){
  constexpr int HC = 4*C;
  int i = blockIdx.x*blockDim.x + threadIdx.x;
  if (i >= n) return;
  float h[IN];
  #pragma unroll
  for (int j = 0; j < IN; ++j) h[j] = hin[i*IN+j];
  #pragma unroll
  for (int o = 0; o < HC; ++o){
    float a = bl[o], r = br[o];
    #pragma unroll
    for (int j = 0; j < IN; ++j){ a += h[j]*wl[j*HC+o]; r += h[j]*wr[j*HC+o]; }
    xl[(size_t)i*HC+o] = a;
    xr[(size_t)i*HC+o] = r;
  }
}

// Fused per-dst aggregation: self-loop + online softmax over CSR in-edges,
// output hout = relu(num/den + bias). Zero atomics; xl[src] gather is L2-resident.
template<int C>
__global__ void k_node_agg(const int* __restrict__ rowstart, const int* __restrict__ csr_src,
                           const float* __restrict__ csr_w, const float* __restrict__ csr_c,
                           const float* __restrict__ xl, const float* __restrict__ xr,
                           const float* __restrict__ la, const float* __restrict__ we,
                           const float* __restrict__ att, const float* __restrict__ bias,
                           float* __restrict__ hout, int n){
  constexpr int HC = 4*C;
  int i = blockIdx.x*blockDim.x + threadIdx.x;
  if (i >= n) return;
  float XR[HC], num[HC];
  const float4* pr = (const float4*)(xr + (size_t)i*HC);
  const float4* pl = (const float4*)(xl + (size_t)i*HC);
  #pragma unroll
  for (int k = 0; k < HC/4; ++k){
    float4 b = pr[k];
    XR[4*k]=b.x; XR[4*k+1]=b.y; XR[4*k+2]=b.z; XR[4*k+3]=b.w;
    float4 a = pl[k];
    num[4*k]=a.x; num[4*k+1]=a.y; num[4*k+2]=a.z; num[4*k+3]=a.w;  // xl_self
  }
  float la0 = la[2*i], la1 = la[2*i+1];
  float m[4], den[4];
  // self-loop term: alpha_self initializes the running max; den=1, num=xl_self.
  #pragma unroll
  for (int hh = 0; hh < 4; ++hh){
    float acc = 0.f;
    #pragma unroll
    for (int c = 0; c < C; ++c){
      int o = hh*C + c;
      float msg = num[o] + XR[o] + la0*we[o] + la1*we[HC+o];
      acc += att[o]*lrelu(msg);
    }
    m[hh] = acc; den[hh] = 1.f;
  }
  int rs = rowstart[i], re = rowstart[i+1];
  for (int j = rs; j < re; ++j){
    int s = csr_src[j];
    float f0 = csr_w[j], f1 = csr_c[j];
    float XL[HC];
    const float4* ps = (const float4*)(xl + (size_t)s*HC);
    #pragma unroll
    for (int k = 0; k < HC/4; ++k){
      float4 a = ps[k];
      XL[4*k]=a.x; XL[4*k+1]=a.y; XL[4*k+2]=a.z; XL[4*k+3]=a.w;
    }
    #pragma unroll
    for (int hh = 0; hh < 4; ++hh){
      float a = 0.f;
      #pragma unroll
      for (int c = 0; c < C; ++c){
        int o = hh*C + c;
        float msg = XL[o] + XR[o] + f0*we[o] + f1*we[HC+o];
        a += att[o]*lrelu(msg);
      }
      float nm = fmaxf(m[hh], a);
      float r  = __expf(m[hh] - nm);
      float ex = __expf(a - nm);
      den[hh] = den[hh]*r + ex;
      #pragma unroll
      for (int c = 0; c < C; ++c){
        int o = hh*C + c;
        num[o] = num[o]*r + ex*XL[o];
      }
      m[hh] = nm;
    }
  }
  #pragma unroll
  for (int o = 0; o < HC; ++o)
    hout[(size_t)i*HC+o] = fmaxf(num[o]/den[o/C] + bias[o], 0.f);
}

// hfc = relu(h2@w_fc+b_fc); asrc = hfc@Wc[2:34], bdst = hfc@Wc[34:66].
__global__ void k_node_final(const float* __restrict__ h2g, const float* __restrict__ wfc,
                             const float* __restrict__ bfc, const float* __restrict__ wc,
                             float* __restrict__ asrc, float* __restrict__ bdst, int n){
  int i = blockIdx.x*blockDim.x + threadIdx.x;
  if (i >= n) return;
  float h2[32];
  const float4* ph = (const float4*)(h2g + (size_t)i*32);
  #pragma unroll
  for (int k = 0; k < 8; ++k){
    float4 v = ph[k];
    h2[4*k]=v.x; h2[4*k+1]=v.y; h2[4*k+2]=v.z; h2[4*k+3]=v.w;
  }
  float a0=0.f, a1=0.f, b0=0.f, b1=0.f;
  for (int o = 0; o < 32; ++o){
    float acc = bfc[o];
    #pragma unroll
    for (int j = 0; j < 32; ++j) acc += h2[j]*wfc[j*32+o];
    float f = fmaxf(acc, 0.f);
    a0 += f*wc[(2+o)*2];   a1 += f*wc[(2+o)*2+1];
    b0 += f*wc[(34+o)*2];  b1 += f*wc[(34+o)*2+1];
  }
  asrc[2*i]=a0; asrc[2*i+1]=a1; bdst[2*i]=b0; bdst[2*i+1]=b1;
}

// out[e] = ef[e]@Wc[0:2] + asrc[src] + bdst[dst] + bc
__global__ void k_edge_final(const int* __restrict__ ei, const float* __restrict__ ew,
                             const float* __restrict__ ce, const float* __restrict__ asrc,
                             const float* __restrict__ bdst, const float* __restrict__ wc,
                             const float* __restrict__ bc, float* __restrict__ out, int E){
  int e = blockIdx.x*blockDim.x + threadIdx.x;
  if (e >= E) return;
  int s = ei[e], d = ei[E+e];
  float f0 = ew[e], f1 = ce[e];
  out[2*e]   = f0*wc[0] + f1*wc[2] + asrc[2*s]   + bdst[2*d]   + bc[0];
  out[2*e+1] = f0*wc[1] + f1*wc[3] + asrc[2*s+1] + bdst[2*d+1] + bc[1];
}

extern "C" void kernel_launch(void* const* d_in, const int* in_sizes, int n_in,
                              void* d_out, int out_size, void* d_ws, size_t ws_size,
                              hipStream_t stream){
  const float* x     = (const float*)d_in[0];
  const int*   ei    = (const int*)  d_in[1];
  const float* ew    = (const float*)d_in[2];
  const float* ce    = (const float*)d_in[3];
  const float* w_init= (const float*)d_in[4];
  const float* b_init= (const float*)d_in[5];
  const float* w1l   = (const float*)d_in[6];
  const float* b1l   = (const float*)d_in[7];
  const float* w1r   = (const float*)d_in[8];
  const float* b1r   = (const float*)d_in[9];
  const float* w1e   = (const float*)d_in[10];
  const float* att1  = (const float*)d_in[11];
  const float* bias1 = (const float*)d_in[12];
  const float* w2l   = (const float*)d_in[13];
  const float* b2l   = (const float*)d_in[14];
  const float* w2r   = (const float*)d_in[15];
  const float* b2r   = (const float*)d_in[16];
  const float* w2e   = (const float*)d_in[17];
  const float* att2  = (const float*)d_in[18];
  const float* bias2 = (const float*)d_in[19];
  const float* w_fc  = (const float*)d_in[20];
  const float* b_fc  = (const float*)d_in[21];
  const float* w_e1  = (const float*)d_in[22];
  const float* b_e1  = (const float*)d_in[23];
  const float* w_e2  = (const float*)d_in[24];
  const float* b_e2  = (const float*)d_in[25];
  float* out = (float*)d_out;

  const int n = in_sizes[0]/5;     // 100000
  const int E = in_sizes[2];       // 3200000

  // ---- workspace layout (4B units) ----
  // [0, n)            deg (int)
  // [n, 2n+1)         rowstart (int)
  // [2n+8, 3n+8)      wptr (int)
  // [3n+8, 5n+8)      la
  // [5n+8, 5n+144)    wc(132)+bc(2)
  // [5n+144, +E)      csr_src (int)
  // [.., +E)          csr_w
  // [.., +E)          csr_c
  // S = node scratch (104n):
  //   h0  @ S        (8n)   dead after pre1
  //   xl1 @ S+8n    (16n)   dead after agg1
  //   xr1 @ S+24n   (16n)   dead after agg1
  //   h1  @ S+40n   (16n)   dead after pre2
  //   xl2 @ S        (32n)  written in pre2 (h0/xl1/xr1 dead)
  //   xr2 @ S+72n   (32n)
  //   h2  @ S+32n   (32n)   written in agg2 (h1 dead)
  //   asrc@ S       (2n), bdst@ S+2n (2n)  written in node_final (xl2 dead)
  int*   W32   = (int*)d_ws;
  float* Wf    = (float*)d_ws;
  int*   deg      = W32;
  int*   rowstart = W32 + (size_t)n;
  int*   wptr     = W32 + (size_t)2*n + 8;
  float* la       = Wf  + (size_t)3*n + 8;
  float* wc       = Wf  + (size_t)5*n + 8;
  float* bc       = wc + 132;
  int*   csr_src  = W32 + (size_t)5*n + 144;
  float* csr_w    = Wf  + (size_t)5*n + 144 + (size_t)E;
  float* csr_c    = Wf  + (size_t)5*n + 144 + (size_t)2*E;
  float* S        = Wf  + (size_t)5*n + 144 + (size_t)3*E;
  float* h0   = S;
  float* xl1  = S + (size_t)8*n;
  float* xr1  = S + (size_t)24*n;
  float* h1   = S + (size_t)40*n;
  float* xl2  = S;
  float* xr2  = S + (size_t)72*n;
  float* h2   = S + (size_t)32*n;
  float* asrc = S;
  float* bdst = S + (size_t)2*n;

  dim3 blk(256);
  dim3 ge((E + 255)/256), gn((n + 255)/256);

  hipMemsetAsync(deg, 0, (size_t)n*sizeof(int), stream);
  k_wcomb<<<1,192,0,stream>>>(w_e1,b_e1,w_e2,b_e2,wc,bc);
  k_node_init<<<gn,blk,0,stream>>>(x,w_init,b_init,h0,n);

  // ---- CSR build ----
  k_hist<<<ge,blk,0,stream>>>(ei,deg,E);
  k_scan<<<1,1024,0,stream>>>(deg,rowstart,wptr,n);
  k_scatter<<<ge,blk,0,stream>>>(ei,ew,ce,wptr,csr_src,csr_w,csr_c,E);
  k_loopattr<<<gn,blk,0,stream>>>(rowstart,csr_w,csr_c,la,n);

  // ---- GATv2 layer 1 (in 8, C=4) ----
  k_node_pre<8,4><<<gn,blk,0,stream>>>(h0,w1l,b1l,w1r,b1r,xl1,xr1,n);
  k_node_agg<4><<<gn,blk,0,stream>>>(rowstart,csr_src,csr_w,csr_c,xl1,xr1,la,w1e,att1,bias1,h1,n);

  // ---- GATv2 layer 2 (in 16, C=8) ----
  k_node_pre<16,8><<<gn,blk,0,stream>>>(h1,w2l,b2l,w2r,b2r,xl2,xr2,n);
  k_node_agg<8><<<gn,blk,0,stream>>>(rowstart,csr_src,csr_w,csr_c,xl2,xr2,la,w2e,att2,bias2,h2,n);

  // ---- fc + folded edge MLP ----
  k_node_final<<<gn,blk,0,stream>>>(h2,w_fc,b_fc,wc,asrc,bdst,n);
  k_edge_final<<<ge,blk,0,stream>>>(ei,ew,ce,asrc,bdst,wc,bc,out,E);
}

// Round 3
// 1128.982 us; speedup vs baseline: 9.5314x; 1.1455x over previous
//
#include <hip/hip_runtime.h>

// KEPCE_GAT r3: CSR aggregation, thread-per-(node,head), 128B-aligned buffers.
// Pipeline: hist -> scan -> scatter(CSR) -> loop_attr
//   -> per layer: node_pre (xl,xr GEMM) -> node_agg4 (4 threads/node, one per
//      head; online softmax over head-slice; zero atomics)
//   -> node_final (fc + folded affine edge-MLP) -> edge_final.

__device__ __forceinline__ float lrelu(float v){ return v > 0.f ? v : 0.2f*v; }

// Fold edge MLP: Wc[66,2] = w_e1[66,32] @ w_e2[32,2]; bc[2] = b_e1@w_e2 + b_e2.
__global__ void k_wcomb(const float* __restrict__ we1, const float* __restrict__ be1,
                        const float* __restrict__ we2, const float* __restrict__ be2,
                        float* __restrict__ wc, float* __restrict__ bc){
  int t = threadIdx.x;
  if (t < 132){
    int i = t >> 1, k = t & 1;
    float acc = 0.f;
    for (int j = 0; j < 32; ++j) acc += we1[i*32+j]*we2[j*2+k];
    wc[t] = acc;
  } else if (t < 134){
    int k = t - 132;
    float acc = be2[k];
    for (int j = 0; j < 32; ++j) acc += be1[j]*we2[j*2+k];
    bc[k] = acc;
  }
}

// h0 = relu(x @ w_init + b_init), x:[n,5] -> h0:[n,8]
__global__ void k_node_init(const float* __restrict__ x, const float* __restrict__ w,
                            const float* __restrict__ b, float* __restrict__ h0, int n){
  int i = blockIdx.x*blockDim.x + threadIdx.x;
  if (i >= n) return;
  float xi[5];
  #pragma unroll
  for (int j = 0; j < 5; ++j) xi[j] = x[i*5+j];
  #pragma unroll
  for (int o = 0; o < 8; ++o){
    float acc = b[o];
    #pragma unroll
    for (int j = 0; j < 5; ++j) acc += xi[j]*w[j*8+o];
    h0[i*8+o] = fmaxf(acc, 0.f);
  }
}

// In-degree histogram.
__global__ void k_hist(const int* __restrict__ ei, int* __restrict__ deg, int E){
  int e = blockIdx.x*blockDim.x + threadIdx.x;
  if (e >= E) return;
  atomicAdd(&deg[ei[E+e]], 1);
}

// Exclusive scan over deg[n] -> rowstart[n+1]; wptr = copy. One block, 1024 thr.
__global__ void k_scan(const int* __restrict__ deg, int* __restrict__ rowstart,
                       int* __restrict__ wptr, int n){
  __shared__ int lds[1024];
  int t = threadIdx.x;
  int chunk = (n + 1023) >> 10;
  int lo = t*chunk, hi = min(n, lo+chunk);
  int s = 0;
  for (int k = lo; k < hi; ++k) s += deg[k];
  lds[t] = s;
  __syncthreads();
  for (int off = 1; off < 1024; off <<= 1){
    int v = (t >= off) ? lds[t-off] : 0;
    __syncthreads();
    lds[t] += v;
    __syncthreads();
  }
  int run = (t == 0) ? 0 : lds[t-1];
  for (int k = lo; k < hi; ++k){
    rowstart[k] = run; wptr[k] = run; run += deg[k];
  }
  if (t == 1023) rowstart[n] = lds[1023];
}

// Scatter edges into CSR order (grouped by dst), permuting src + edge attrs.
__global__ void k_scatter(const int* __restrict__ ei, const float* __restrict__ ew,
                          const float* __restrict__ ce, int* __restrict__ wptr,
                          int* __restrict__ csr_src, float* __restrict__ csr_w,
                          float* __restrict__ csr_c, int E){
  int e = blockIdx.x*blockDim.x + threadIdx.x;
  if (e >= E) return;
  int s = ei[e], d = ei[E+e];
  int pos = atomicAdd(&wptr[d], 1);
  csr_src[pos] = s;
  csr_w[pos]   = ew[e];
  csr_c[pos]   = ce[e];
}

// Per-node mean of incoming edge attrs (self-loop fill_value='mean').
__global__ void k_loopattr(const int* __restrict__ rowstart, const float* __restrict__ csr_w,
                           const float* __restrict__ csr_c, float* __restrict__ la, int n){
  int i = blockIdx.x*blockDim.x + threadIdx.x;
  if (i >= n) return;
  int rs = rowstart[i], re = rowstart[i+1];
  float sw = 0.f, sc = 0.f;
  for (int j = rs; j < re; ++j){ sw += csr_w[j]; sc += csr_c[j]; }
  float inv = 1.f / fmaxf((float)(re - rs), 1.f);
  la[2*i]   = sw*inv;
  la[2*i+1] = sc*inv;
}

// xl = hin@Wl+bl, xr = hin@Wr+br.
template<int IN, int C>
__global__ void k_node_pre(const float* __restrict__ hin,
                           const float* __restrict__ wl, const float* __restrict__ bl,
                           const float* __restrict__ wr, const float* __restrict__ br,
                           float* __restrict__ xl, float* __restrict__ xr, int n){
  constexpr int HC = 4*C;
  int i = blockIdx.x*blockDim.x + threadIdx.x;
  if (i >= n) return;
  float h[IN];
  #pragma unroll
  for (int j = 0; j < IN; ++j) h[j] = hin[i*IN+j];
  #pragma unroll
  for (int o = 0; o < HC; ++o){
    float a = bl[o], r = br[o];
    #pragma unroll
    for (int j = 0; j < IN; ++j){ a += h[j]*wl[j*HC+o]; r += h[j]*wr[j*HC+o]; }
    xl[(size_t)i*HC+o] = a;
    xr[(size_t)i*HC+o] = r;
  }
}

// Fused per-(dst,head) aggregation: 4 threads per node (one per head), each
// handles the C-float head slice. Self-loop + online softmax over CSR in-edges.
// hout = relu(num/den + bias). Zero atomics; head-lanes of a node read
// consecutive 16/32B chunks of the same xl row -> one coalesced transaction.
template<int C>
__global__ void k_node_agg4(const int* __restrict__ rowstart, const int* __restrict__ csr_src,
                            const float* __restrict__ csr_w, const float* __restrict__ csr_c,
                            const float* __restrict__ xl, const float* __restrict__ xr,
                            const float* __restrict__ la, const float* __restrict__ we,
                            const float* __restrict__ att, const float* __restrict__ bias,
                            float* __restrict__ hout, int n){
  constexpr int HC = 4*C;
  int t = blockIdx.x*blockDim.x + threadIdx.x;
  int i = t >> 2, head = t & 3;
  if (i >= n) return;

  // per-head constants
  float weA[C], weB[C], AT[C], BS[C];
  #pragma unroll
  for (int c = 0; c < C; ++c){
    int o = head*C + c;
    weA[c] = we[o]; weB[c] = we[HC+o]; AT[c] = att[o]; BS[c] = bias[o];
  }
  float XR[C], num[C];
  {
    const float4* pr = (const float4*)(xr + (size_t)i*HC + head*C);
    const float4* pl = (const float4*)(xl + (size_t)i*HC + head*C);
    #pragma unroll
    for (int k = 0; k < C/4; ++k){
      float4 b = pr[k];
      XR[4*k]=b.x; XR[4*k+1]=b.y; XR[4*k+2]=b.z; XR[4*k+3]=b.w;
      float4 a = pl[k];
      num[4*k]=a.x; num[4*k+1]=a.y; num[4*k+2]=a.z; num[4*k+3]=a.w;  // xl_self
    }
  }
  float la0 = la[2*i], la1 = la[2*i+1];
  // self-loop term initializes the online-softmax state.
  float m = 0.f;
  #pragma unroll
  for (int c = 0; c < C; ++c)
    m += AT[c]*lrelu(num[c] + XR[c] + la0*weA[c] + la1*weB[c]);
  float den = 1.f;

  int rs = rowstart[i], re = rowstart[i+1];
  for (int j = rs; j < re; ++j){
    int s = csr_src[j];
    float f0 = csr_w[j], f1 = csr_c[j];
    float XL[C];
    const float4* ps = (const float4*)(xl + (size_t)s*HC + head*C);
    #pragma unroll
    for (int k = 0; k < C/4; ++k){
      float4 a = ps[k];
      XL[4*k]=a.x; XL[4*k+1]=a.y; XL[4*k+2]=a.z; XL[4*k+3]=a.w;
    }
    float a = 0.f;
    #pragma unroll
    for (int c = 0; c < C; ++c)
      a += AT[c]*lrelu(XL[c] + XR[c] + f0*weA[c] + f1*weB[c]);
    float nm = fmaxf(m, a);
    float r  = __expf(m - nm);
    float ex = __expf(a - nm);
    den = den*r + ex;
    #pragma unroll
    for (int c = 0; c < C; ++c) num[c] = num[c]*r + ex*XL[c];
    m = nm;
  }
  float inv = 1.f / den;
  #pragma unroll
  for (int c = 0; c < C; ++c)
    hout[(size_t)i*HC + head*C + c] = fmaxf(num[c]*inv + BS[c], 0.f);
}

// hfc = relu(h2@w_fc+b_fc); asrc = hfc@Wc[2:34], bdst = hfc@Wc[34:66].
__global__ void k_node_final(const float* __restrict__ h2g, const float* __restrict__ wfc,
                             const float* __restrict__ bfc, const float* __restrict__ wc,
                             float* __restrict__ asrc, float* __restrict__ bdst, int n){
  int i = blockIdx.x*blockDim.x + threadIdx.x;
  if (i >= n) return;
  float h2[32];
  const float4* ph = (const float4*)(h2g + (size_t)i*32);
  #pragma unroll
  for (int k = 0; k < 8; ++k){
    float4 v = ph[k];
    h2[4*k]=v.x; h2[4*k+1]=v.y; h2[4*k+2]=v.z; h2[4*k+3]=v.w;
  }
  float a0=0.f, a1=0.f, b0=0.f, b1=0.f;
  for (int o = 0; o < 32; ++o){
    float acc = bfc[o];
    #pragma unroll
    for (int j = 0; j < 32; ++j) acc += h2[j]*wfc[j*32+o];
    float f = fmaxf(acc, 0.f);
    a0 += f*wc[(2+o)*2];   a1 += f*wc[(2+o)*2+1];
    b0 += f*wc[(34+o)*2];  b1 += f*wc[(34+o)*2+1];
  }
  asrc[2*i]=a0; asrc[2*i+1]=a1; bdst[2*i]=b0; bdst[2*i+1]=b1;
}

// out[e] = ef[e]@Wc[0:2] + asrc[src] + bdst[dst] + bc
__global__ void k_edge_final(const int* __restrict__ ei, const float* __restrict__ ew,
                             const float* __restrict__ ce, const float* __restrict__ asrc,
                             const float* __restrict__ bdst, const float* __restrict__ wc,
                             const float* __restrict__ bc, float* __restrict__ out, int E){
  int e = blockIdx.x*blockDim.x + threadIdx.x;
  if (e >= E) return;
  int s = ei[e], d = ei[E+e];
  float f0 = ew[e], f1 = ce[e];
  out[2*e]   = f0*wc[0] + f1*wc[2] + asrc[2*s]   + bdst[2*d]   + bc[0];
  out[2*e+1] = f0*wc[1] + f1*wc[3] + asrc[2*s+1] + bdst[2*d+1] + bc[1];
}

extern "C" void kernel_launch(void* const* d_in, const int* in_sizes, int n_in,
                              void* d_out, int out_size, void* d_ws, size_t ws_size,
                              hipStream_t stream){
  const float* x     = (const float*)d_in[0];
  const int*   ei    = (const int*)  d_in[1];
  const float* ew    = (const float*)d_in[2];
  const float* ce    = (const float*)d_in[3];
  const float* w_init= (const float*)d_in[4];
  const float* b_init= (const float*)d_in[5];
  const float* w1l   = (const float*)d_in[6];
  const float* b1l   = (const float*)d_in[7];
  const float* w1r   = (const float*)d_in[8];
  const float* b1r   = (const float*)d_in[9];
  const float* w1e   = (const float*)d_in[10];
  const float* att1  = (const float*)d_in[11];
  const float* bias1 = (const float*)d_in[12];
  const float* w2l   = (const float*)d_in[13];
  const float* b2l   = (const float*)d_in[14];
  const float* w2r   = (const float*)d_in[15];
  const float* b2r   = (const float*)d_in[16];
  const float* w2e   = (const float*)d_in[17];
  const float* att2  = (const float*)d_in[18];
  const float* bias2 = (const float*)d_in[19];
  const float* w_fc  = (const float*)d_in[20];
  const float* b_fc  = (const float*)d_in[21];
  const float* w_e1  = (const float*)d_in[22];
  const float* b_e1  = (const float*)d_in[23];
  const float* w_e2  = (const float*)d_in[24];
  const float* b_e2  = (const float*)d_in[25];
  float* out = (float*)d_out;

  const int n = in_sizes[0]/5;     // 100000
  const int E = in_sizes[2];       // 3200000

  // ---- workspace layout: every array 128B-aligned (32-float units) ----
  int*   W32 = (int*)d_ws;
  float* Wf  = (float*)d_ws;
  size_t off = 0;
  auto nxt = [&off](size_t cnt){ size_t p = off; off += (cnt + 31) & ~(size_t)31; return p; };
  int*   deg      = W32 + nxt(n);
  int*   rowstart = W32 + nxt((size_t)n + 1);
  int*   wptr     = W32 + nxt(n);
  float* la       = Wf  + nxt((size_t)2*n);
  float* wc       = Wf  + nxt(160);
  float* bc       = wc + 132;
  int*   csr_src  = W32 + nxt(E);
  float* csr_w    = Wf  + nxt(E);
  float* csr_c    = Wf  + nxt(E);
  // node scratch region S (120 na floats), aliased across phases:
  size_t na = ((size_t)n + 31) & ~(size_t)31;
  float* S    = Wf + nxt(120*na);
  float* h0   = S;              // 8n,  dead after pre1
  float* xl1  = S + 8*na;       // 16n, dead after agg1
  float* xr1  = S + 24*na;      // 16n, dead after agg1
  float* h1   = S + 40*na;      // 16n, dead after pre2
  float* xl2  = S;              // 32n  (over h0/xl1/xr1)
  float* xr2  = S + 56*na;      // 32n
  float* h2   = S + 88*na;      // 32n
  float* asrc = S;              // 2n   (over xl2, dead)
  float* bdst = S + 2*na;       // 2n

  dim3 blk(256);
  dim3 ge((E + 255)/256), gn((n + 255)/256), gn4(((size_t)4*n + 255)/256);

  hipMemsetAsync(deg, 0, (size_t)n*sizeof(int), stream);
  k_wcomb<<<1,192,0,stream>>>(w_e1,b_e1,w_e2,b_e2,wc,bc);
  k_node_init<<<gn,blk,0,stream>>>(x,w_init,b_init,h0,n);

  // ---- CSR build ----
  k_hist<<<ge,blk,0,stream>>>(ei,deg,E);
  k_scan<<<1,1024,0,stream>>>(deg,rowstart,wptr,n);
  k_scatter<<<ge,blk,0,stream>>>(ei,ew,ce,wptr,csr_src,csr_w,csr_c,E);
  k_loopattr<<<gn,blk,0,stream>>>(rowstart,csr_w,csr_c,la,n);

  // ---- GATv2 layer 1 (in 8, C=4) ----
  k_node_pre<8,4><<<gn,blk,0,stream>>>(h0,w1l,b1l,w1r,b1r,xl1,xr1,n);
  k_node_agg4<4><<<gn4,blk,0,stream>>>(rowstart,csr_src,csr_w,csr_c,xl1,xr1,la,w1e,att1,bias1,h1,n);

  // ---- GATv2 layer 2 (in 16, C=8) ----
  k_node_pre<16,8><<<gn,blk,0,stream>>>(h1,w2l,b2l,w2r,b2r,xl2,xr2,n);
  k_node_agg4<8><<<gn4,blk,0,stream>>>(rowstart,csr_src,csr_w,csr_c,xl2,xr2,la,w2e,att2,bias2,h2,n);

  // ---- fc + folded edge MLP ----
  k_node_final<<<gn,blk,0,stream>>>(h2,w_fc,b_fc,wc,asrc,bdst,n);
  k_edge_final<<<ge,blk,0,stream>>>(ei,ew,ce,asrc,bdst,wc,bc,out,E);
}

// Round 4
// 962.507 us; speedup vs baseline: 11.1799x; 1.1730x over previous
//
#include <hip/hip_runtime.h>

// KEPCE_GAT r4: packed int4 CSR (1 store/edge in scatter), loopattr folded
// into agg (self-loop applied last), node_init fused into pre1, node_final
// fused into agg2 via LDS + shfl reduce. 10 dispatches.

__device__ __forceinline__ float lrelu(float v){ return v > 0.f ? v : 0.2f*v; }

// Fold edge MLP: Wc[66,2] = w_e1[66,32] @ w_e2[32,2]; bc[2] = b_e1@w_e2 + b_e2.
__global__ void k_wcomb(const float* __restrict__ we1, const float* __restrict__ be1,
                        const float* __restrict__ we2, const float* __restrict__ be2,
                        float* __restrict__ wc, float* __restrict__ bc){
  int t = threadIdx.x;
  if (t < 132){
    int i = t >> 1, k = t & 1;
    float acc = 0.f;
    for (int j = 0; j < 32; ++j) acc += we1[i*32+j]*we2[j*2+k];
    wc[t] = acc;
  } else if (t < 134){
    int k = t - 132;
    float acc = be2[k];
    for (int j = 0; j < 32; ++j) acc += be1[j]*we2[j*2+k];
    bc[k] = acc;
  }
}

// In-degree histogram, 4 edges/thread (E assumed %4==0 fast path w/ tail).
__global__ void k_hist(const int* __restrict__ dst, int* __restrict__ deg, int E){
  int t = blockIdx.x*blockDim.x + threadIdx.x;
  int base = t << 2;
  if (base + 4 <= E){
    int4 d = *(const int4*)(dst + base);
    atomicAdd(&deg[d.x], 1); atomicAdd(&deg[d.y], 1);
    atomicAdd(&deg[d.z], 1); atomicAdd(&deg[d.w], 1);
  } else {
    for (int k = base; k < E; ++k) atomicAdd(&deg[dst[k]], 1);
  }
}

// Exclusive scan over deg[n] -> rowstart[n+1]; wptr = copy. One block, 1024 thr.
__global__ void k_scan(const int* __restrict__ deg, int* __restrict__ rowstart,
                       int* __restrict__ wptr, int n){
  __shared__ int lds[1024];
  int t = threadIdx.x;
  int chunk = (n + 1023) >> 10;
  int lo = t*chunk, hi = min(n, lo+chunk);
  int s = 0;
  for (int k = lo; k < hi; ++k) s += deg[k];
  lds[t] = s;
  __syncthreads();
  for (int off = 1; off < 1024; off <<= 1){
    int v = (t >= off) ? lds[t-off] : 0;
    __syncthreads();
    lds[t] += v;
    __syncthreads();
  }
  int run = (t == 0) ? 0 : lds[t-1];
  for (int k = lo; k < hi; ++k){
    rowstart[k] = run; wptr[k] = run; run += deg[k];
  }
  if (t == 1023) rowstart[n] = lds[1023];
}

// Scatter edges into CSR order: ONE 16B store per edge {src, w, c, 0}.
__global__ void k_scatter(const int* __restrict__ ei, const float* __restrict__ ew,
                          const float* __restrict__ ce, int* __restrict__ wptr,
                          int4* __restrict__ csr, int E){
  int e = blockIdx.x*blockDim.x + threadIdx.x;
  if (e >= E) return;
  int s = ei[e], d = ei[E+e];
  int pos = atomicAdd(&wptr[d], 1);
  csr[pos] = make_int4(s, __float_as_int(ew[e]), __float_as_int(ce[e]), 0);
}

// Fused init+pre layer1: h0 = relu(x@wi+bi) in regs; xl1/xr1 = h0@Wl/Wr + b.
__global__ void k_pre1(const float* __restrict__ x, const float* __restrict__ wi,
                       const float* __restrict__ bi, const float* __restrict__ wl,
                       const float* __restrict__ bl, const float* __restrict__ wr,
                       const float* __restrict__ br, float* __restrict__ xl,
                       float* __restrict__ xr, int n){
  int i = blockIdx.x*blockDim.x + threadIdx.x;
  if (i >= n) return;
  float xi[5];
  #pragma unroll
  for (int j = 0; j < 5; ++j) xi[j] = x[i*5+j];
  float h[8];
  #pragma unroll
  for (int o = 0; o < 8; ++o){
    float acc = bi[o];
    #pragma unroll
    for (int j = 0; j < 5; ++j) acc += xi[j]*wi[j*8+o];
    h[o] = fmaxf(acc, 0.f);
  }
  #pragma unroll
  for (int o = 0; o < 16; ++o){
    float a = bl[o], r = br[o];
    #pragma unroll
    for (int j = 0; j < 8; ++j){ a += h[j]*wl[j*16+o]; r += h[j]*wr[j*16+o]; }
    xl[(size_t)i*16+o] = a;
    xr[(size_t)i*16+o] = r;
  }
}

// xl = hin@Wl+bl, xr = hin@Wr+br (layer2: 16 -> 32).
__global__ void k_pre2(const float* __restrict__ hin,
                       const float* __restrict__ wl, const float* __restrict__ bl,
                       const float* __restrict__ wr, const float* __restrict__ br,
                       float* __restrict__ xl, float* __restrict__ xr, int n){
  int i = blockIdx.x*blockDim.x + threadIdx.x;
  if (i >= n) return;
  float h[16];
  #pragma unroll
  for (int j = 0; j < 16; ++j) h[j] = hin[(size_t)i*16+j];
  #pragma unroll
  for (int o = 0; o < 32; ++o){
    float a = bl[o], r = br[o];
    #pragma unroll
    for (int j = 0; j < 16; ++j){ a += h[j]*wl[j*32+o]; r += h[j]*wr[j*32+o]; }
    xl[(size_t)i*32+o] = a;
    xr[(size_t)i*32+o] = r;
  }
}

// Layer-1 aggregation: 4 threads/node (one per head), C=4. Online softmax over
// CSR edges (2-way unrolled), edge-attr mean accumulated in-loop, self-loop
// applied last. Writes h1 = relu(num/den + bias).
__global__ void k_agg1(const int* __restrict__ rowstart, const int4* __restrict__ csr,
                       const float* __restrict__ xl, const float* __restrict__ xr,
                       const float* __restrict__ we, const float* __restrict__ att,
                       const float* __restrict__ bias, float* __restrict__ hout, int n){
  constexpr int C = 4, HC = 16;
  int t = blockIdx.x*blockDim.x + threadIdx.x;
  int i = t >> 2, head = t & 3;
  if (i >= n) return;
  float weA[C], weB[C], AT[C], BS[C];
  #pragma unroll
  for (int c = 0; c < C; ++c){
    int o = head*C + c;
    weA[c] = we[o]; weB[c] = we[HC+o]; AT[c] = att[o]; BS[c] = bias[o];
  }
  float XR[C];
  {
    float4 b = *(const float4*)(xr + (size_t)i*HC + head*C);
    XR[0]=b.x; XR[1]=b.y; XR[2]=b.z; XR[3]=b.w;
  }
  float m = -3.0e38f, den = 0.f, sw = 0.f, sc = 0.f;
  float num[C] = {0.f,0.f,0.f,0.f};
  int rs = rowstart[i], re = rowstart[i+1];
  int j = rs;
  for (; j + 2 <= re; j += 2){
    int4 pa = csr[j], pb = csr[j+1];
    float4 qa = *(const float4*)(xl + (size_t)pa.x*HC + head*C);
    float4 qb = *(const float4*)(xl + (size_t)pb.x*HC + head*C);
    float f0a = __int_as_float(pa.y), f1a = __int_as_float(pa.z);
    float f0b = __int_as_float(pb.y), f1b = __int_as_float(pb.z);
    sw += f0a + f0b; sc += f1a + f1b;
    float XA[C] = {qa.x,qa.y,qa.z,qa.w};
    float XB[C] = {qb.x,qb.y,qb.z,qb.w};
    float aa = 0.f, ab = 0.f;
    #pragma unroll
    for (int c = 0; c < C; ++c) aa += AT[c]*lrelu(XA[c] + XR[c] + f0a*weA[c] + f1a*weB[c]);
    #pragma unroll
    for (int c = 0; c < C; ++c) ab += AT[c]*lrelu(XB[c] + XR[c] + f0b*weA[c] + f1b*weB[c]);
    float nm = fmaxf(m, aa);
    float r = __expf(m - nm), ex = __expf(aa - nm);
    den = den*r + ex;
    #pragma unroll
    for (int c = 0; c < C; ++c) num[c] = num[c]*r + ex*XA[c];
    m = nm;
    nm = fmaxf(m, ab); r = __expf(m - nm); ex = __expf(ab - nm);
    den = den*r + ex;
    #pragma unroll
    for (int c = 0; c < C; ++c) num[c] = num[c]*r + ex*XB[c];
    m = nm;
  }
  if (j < re){
    int4 pa = csr[j];
    float4 qa = *(const float4*)(xl + (size_t)pa.x*HC + head*C);
    float f0a = __int_as_float(pa.y), f1a = __int_as_float(pa.z);
    sw += f0a; sc += f1a;
    float XA[C] = {qa.x,qa.y,qa.z,qa.w};
    float aa = 0.f;
    #pragma unroll
    for (int c = 0; c < C; ++c) aa += AT[c]*lrelu(XA[c] + XR[c] + f0a*weA[c] + f1a*weB[c]);
    float nm = fmaxf(m, aa);
    float r = __expf(m - nm), ex = __expf(aa - nm);
    den = den*r + ex;
    #pragma unroll
    for (int c = 0; c < C; ++c) num[c] = num[c]*r + ex*XA[c];
    m = nm;
  }
  // self-loop last (mean edge attrs from in-loop sums)
  float cf = fmaxf((float)(re - rs), 1.f);
  float la0 = sw/cf, la1 = sc/cf;
  float4 qs = *(const float4*)(xl + (size_t)i*HC + head*C);
  float XS[C] = {qs.x,qs.y,qs.z,qs.w};
  float as = 0.f;
  #pragma unroll
  for (int c = 0; c < C; ++c) as += AT[c]*lrelu(XS[c] + XR[c] + la0*weA[c] + la1*weB[c]);
  float nm = fmaxf(m, as);
  float r = __expf(m - nm), ex = __expf(as - nm);
  den = den*r + ex;
  #pragma unroll
  for (int c = 0; c < C; ++c) num[c] = num[c]*r + ex*XS[c];
  float inv = 1.f/den;
  #pragma unroll
  for (int c = 0; c < C; ++c)
    hout[(size_t)i*HC + head*C + c] = fmaxf(num[c]*inv + BS[c], 0.f);
}

// Layer-2 aggregation (C=8) with node_final fused: after per-head h2 slice is
// computed, exchange via LDS, split the 32x32 fc across the node's 4 threads,
// fold into asrc/bdst via wc, shfl_xor reduce. No h2 global round-trip.
__global__ void k_agg2f(const int* __restrict__ rowstart, const int4* __restrict__ csr,
                        const float* __restrict__ xl, const float* __restrict__ xr,
                        const float* __restrict__ we, const float* __restrict__ att,
                        const float* __restrict__ bias, const float* __restrict__ wfc,
                        const float* __restrict__ bfc, const float* __restrict__ wc,
                        float* __restrict__ asrc, float* __restrict__ bdst, int n){
  constexpr int C = 8, HC = 32;
  __shared__ float s_h[64*33];
  __shared__ float s_w[1024];
  __shared__ float s_wc[134];
  int lt = threadIdx.x;
  for (int k = lt; k < 1024; k += 256) s_w[k] = wfc[k];
  if (lt < 134) s_wc[lt] = wc[lt];
  int t = blockIdx.x*blockDim.x + lt;
  int i = t >> 2, head = t & 3;
  bool valid = i < n;
  int ic = valid ? i : 0;
  float weA[C], weB[C], AT[C], BS[C];
  #pragma unroll
  for (int c = 0; c < C; ++c){
    int o = head*C + c;
    weA[c] = we[o]; weB[c] = we[HC+o]; AT[c] = att[o]; BS[c] = bias[o];
  }
  float XR[C];
  {
    const float4* pr = (const float4*)(xr + (size_t)ic*HC + head*C);
    float4 b0 = pr[0], b1 = pr[1];
    XR[0]=b0.x; XR[1]=b0.y; XR[2]=b0.z; XR[3]=b0.w;
    XR[4]=b1.x; XR[5]=b1.y; XR[6]=b1.z; XR[7]=b1.w;
  }
  float m = -3.0e38f, den = 0.f, sw = 0.f, sc = 0.f;
  float num[C] = {0.f,0.f,0.f,0.f,0.f,0.f,0.f,0.f};
  int rs = 0, re = 0;
  if (valid){ rs = rowstart[i]; re = rowstart[i+1]; }
  int j = rs;
  for (; j + 2 <= re; j += 2){
    int4 pa = csr[j], pb = csr[j+1];
    const float4* qa = (const float4*)(xl + (size_t)pa.x*HC + head*C);
    const float4* qb = (const float4*)(xl + (size_t)pb.x*HC + head*C);
    float4 a0 = qa[0], a1 = qa[1], b0 = qb[0], b1 = qb[1];
    float f0a = __int_as_float(pa.y), f1a = __int_as_float(pa.z);
    float f0b = __int_as_float(pb.y), f1b = __int_as_float(pb.z);
    sw += f0a + f0b; sc += f1a + f1b;
    float XA[C] = {a0.x,a0.y,a0.z,a0.w,a1.x,a1.y,a1.z,a1.w};
    float XB[C] = {b0.x,b0.y,b0.z,b0.w,b1.x,b1.y,b1.z,b1.w};
    float aa = 0.f, ab = 0.f;
    #pragma unroll
    for (int c = 0; c < C; ++c) aa += AT[c]*lrelu(XA[c] + XR[c] + f0a*weA[c] + f1a*weB[c]);
    #pragma unroll
    for (int c = 0; c < C; ++c) ab += AT[c]*lrelu(XB[c] + XR[c] + f0b*weA[c] + f1b*weB[c]);
    float nm = fmaxf(m, aa);
    float r = __expf(m - nm), ex = __expf(aa - nm);
    den = den*r + ex;
    #pragma unroll
    for (int c = 0; c < C; ++c) num[c] = num[c]*r + ex*XA[c];
    m = nm;
    nm = fmaxf(m, ab); r = __expf(m - nm); ex = __expf(ab - nm);
    den = den*r + ex;
    #pragma unroll
    for (int c = 0; c < C; ++c) num[c] = num[c]*r + ex*XB[c];
    m = nm;
  }
  if (j < re){
    int4 pa = csr[j];
    const float4* qa = (const float4*)(xl + (size_t)pa.x*HC + head*C);
    float4 a0 = qa[0], a1 = qa[1];
    float f0a = __int_as_float(pa.y), f1a = __int_as_float(pa.z);
    sw += f0a; sc += f1a;
    float XA[C] = {a0.x,a0.y,a0.z,a0.w,a1.x,a1.y,a1.z,a1.w};
    float aa = 0.f;
    #pragma unroll
    for (int c = 0; c < C; ++c) aa += AT[c]*lrelu(XA[c] + XR[c] + f0a*weA[c] + f1a*weB[c]);
    float nm = fmaxf(m, aa);
    float r = __expf(m - nm), ex = __expf(aa - nm);
    den = den*r + ex;
    #pragma unroll
    for (int c = 0; c < C; ++c) num[c] = num[c]*r + ex*XA[c];
    m = nm;
  }
  float out8[C];
  if (valid){
    float cf = fmaxf((float)(re - rs), 1.f);
    float la0 = sw/cf, la1 = sc/cf;
    const float4* pl = (const float4*)(xl + (size_t)i*HC + head*C);
    float4 s0 = pl[0], s1 = pl[1];
    float XS[C] = {s0.x,s0.y,s0.z,s0.w,s1.x,s1.y,s1.z,s1.w};
    float as = 0.f;
    #pragma unroll
    for (int c = 0; c < C; ++c) as += AT[c]*lrelu(XS[c] + XR[c] + la0*weA[c] + la1*weB[c]);
    float nm = fmaxf(m, as);
    float r = __expf(m - nm), ex = __expf(as - nm);
    den = den*r + ex;
    #pragma unroll
    for (int c = 0; c < C; ++c) num[c] = num[c]*r + ex*XS[c];
    float inv = 1.f/den;
    #pragma unroll
    for (int c = 0; c < C; ++c) out8[c] = fmaxf(num[c]*inv + BS[c], 0.f);
  } else {
    #pragma unroll
    for (int c = 0; c < C; ++c) out8[c] = 0.f;
  }
  int ln = lt >> 2;
  #pragma unroll
  for (int c = 0; c < C; ++c) s_h[ln*33 + head*C + c] = out8[c];
  __syncthreads();
  float hl[32];
  #pragma unroll
  for (int j2 = 0; j2 < 32; ++j2) hl[j2] = s_h[ln*33 + j2];
  float pa0=0.f, pa1=0.f, pb0=0.f, pb1=0.f;
  #pragma unroll
  for (int oc = 0; oc < 8; ++oc){
    int o = head*8 + oc;
    float acc = bfc[o];
    #pragma unroll
    for (int j2 = 0; j2 < 32; ++j2) acc += hl[j2]*s_w[j2*32+o];
    float f = fmaxf(acc, 0.f);
    pa0 += f*s_wc[(2+o)*2];  pa1 += f*s_wc[(2+o)*2+1];
    pb0 += f*s_wc[(34+o)*2]; pb1 += f*s_wc[(34+o)*2+1];
  }
  pa0 += __shfl_xor(pa0,1); pa0 += __shfl_xor(pa0,2);
  pa1 += __shfl_xor(pa1,1); pa1 += __shfl_xor(pa1,2);
  pb0 += __shfl_xor(pb0,1); pb0 += __shfl_xor(pb0,2);
  pb1 += __shfl_xor(pb1,1); pb1 += __shfl_xor(pb1,2);
  if (valid){
    if (head == 0)      ((float2*)asrc)[i] = make_float2(pa0, pa1);
    else if (head == 1) ((float2*)bdst)[i] = make_float2(pb0, pb1);
  }
}

// out[e] = ef[e]@Wc[0:2] + asrc[src] + bdst[dst] + bc  (float2 store)
__global__ void k_edge_final(const int* __restrict__ ei, const float* __restrict__ ew,
                             const float* __restrict__ ce, const float* __restrict__ asrc,
                             const float* __restrict__ bdst, const float* __restrict__ wc,
                             const float* __restrict__ bc, float2* __restrict__ out, int E){
  int e = blockIdx.x*blockDim.x + threadIdx.x;
  if (e >= E) return;
  int s = ei[e], d = ei[E+e];
  float f0 = ew[e], f1 = ce[e];
  float2 a = ((const float2*)asrc)[s];
  float2 b = ((const float2*)bdst)[d];
  out[e] = make_float2(f0*wc[0] + f1*wc[2] + a.x + b.x + bc[0],
                       f0*wc[1] + f1*wc[3] + a.y + b.y + bc[1]);
}

extern "C" void kernel_launch(void* const* d_in, const int* in_sizes, int n_in,
                              void* d_out, int out_size, void* d_ws, size_t ws_size,
                              hipStream_t stream){
  const float* x     = (const float*)d_in[0];
  const int*   ei    = (const int*)  d_in[1];
  const float* ew    = (const float*)d_in[2];
  const float* ce    = (const float*)d_in[3];
  const float* w_init= (const float*)d_in[4];
  const float* b_init= (const float*)d_in[5];
  const float* w1l   = (const float*)d_in[6];
  const float* b1l   = (const float*)d_in[7];
  const float* w1r   = (const float*)d_in[8];
  const float* b1r   = (const float*)d_in[9];
  const float* w1e   = (const float*)d_in[10];
  const float* att1  = (const float*)d_in[11];
  const float* bias1 = (const float*)d_in[12];
  const float* w2l   = (const float*)d_in[13];
  const float* b2l   = (const float*)d_in[14];
  const float* w2r   = (const float*)d_in[15];
  const float* b2r   = (const float*)d_in[16];
  const float* w2e   = (const float*)d_in[17];
  const float* att2  = (const float*)d_in[18];
  const float* bias2 = (const float*)d_in[19];
  const float* w_fc  = (const float*)d_in[20];
  const float* b_fc  = (const float*)d_in[21];
  const float* w_e1  = (const float*)d_in[22];
  const float* b_e1  = (const float*)d_in[23];
  const float* w_e2  = (const float*)d_in[24];
  const float* b_e2  = (const float*)d_in[25];

  const int n = in_sizes[0]/5;     // 100000
  const int E = in_sizes[2];       // 3200000

  // ---- workspace layout: 128B-aligned (32 x 4B units) ----
  int*   W32 = (int*)d_ws;
  float* Wf  = (float*)d_ws;
  size_t off = 0;
  auto nxt = [&off](size_t cnt){ size_t p = off; off += (cnt + 31) & ~(size_t)31; return p; };
  int*   deg      = W32 + nxt(n);
  int*   rowstart = W32 + nxt((size_t)n + 1);
  int*   wptr     = W32 + nxt(n);
  float* wc       = Wf  + nxt(160);
  float* bc       = wc + 132;
  int4*  csr      = (int4*)(W32 + nxt((size_t)4*E));
  size_t na = ((size_t)n + 31) & ~(size_t)31;
  float* S    = Wf + nxt(80*na);
  float* xl1  = S;              // 16n, dead after agg1
  float* xr1  = S + 16*na;      // 16n, dead after agg1
  float* h1   = S + 32*na;      // 16n, dead after pre2
  float* xl2  = S;              // 32n (over xl1/xr1)
  float* xr2  = S + 48*na;      // 32n
  float* asrc = S + 32*na;      // 2n  (over h1, dead)
  float* bdst = S + 34*na;      // 2n

  dim3 blk(256);
  dim3 ge((E + 255)/256), gn((n + 255)/256);
  dim3 ge4(((E + 3)/4 + 255)/256), gn4(((size_t)4*n + 255)/256);

  hipMemsetAsync(deg, 0, (size_t)n*sizeof(int), stream);
  k_wcomb<<<1,192,0,stream>>>(w_e1,b_e1,w_e2,b_e2,wc,bc);

  // ---- CSR build ----
  k_hist<<<ge4,blk,0,stream>>>(ei + E, deg, E);
  k_scan<<<1,1024,0,stream>>>(deg,rowstart,wptr,n);
  k_scatter<<<ge,blk,0,stream>>>(ei,ew,ce,wptr,csr,E);

  // ---- GATv2 layer 1 (in 8, C=4) ----
  k_pre1<<<gn,blk,0,stream>>>(x,w_init,b_init,w1l,b1l,w1r,b1r,xl1,xr1,n);
  k_agg1<<<gn4,blk,0,stream>>>(rowstart,csr,xl1,xr1,w1e,att1,bias1,h1,n);

  // ---- GATv2 layer 2 (in 16, C=8) + fused fc/edge-MLP node terms ----
  k_pre2<<<gn,blk,0,stream>>>(h1,w2l,b2l,w2r,b2r,xl2,xr2,n);
  k_agg2f<<<gn4,blk,0,stream>>>(rowstart,csr,xl2,xr2,w2e,att2,bias2,w_fc,b_fc,wc,asrc,bdst,n);

  // ---- edge scores ----
  k_edge_final<<<ge,blk,0,stream>>>(ei,ew,ce,asrc,bdst,wc,bc,(float2*)d_out,E);
}